// Round 3
// baseline (1610.685 us; speedup 1.0000x reference)
//
#include <hip/hip_runtime.h>

#define DIN 512
#define DH  64
#define BKT_SHIFT 7                 // 128 nodes per bucket
#define BKT_NODES (1 << BKT_SHIFT)

// ---------------- small precompute: Wc = W2@Wlin, bias_out = b2@Wlin + blin ----
__global__ __launch_bounds__(256) void k_wc(const float* __restrict__ W2,
                                            const float* __restrict__ b2,
                                            const float* __restrict__ Wlin,
                                            const float* __restrict__ blin,
                                            float* __restrict__ Wc,
                                            float* __restrict__ bias_out) {
  int tid = threadIdx.x;
  for (int idx = tid; idx < 64 * 64; idx += 256) {
    int i = idx >> 6, j = idx & 63;
    float s = 0.f;
    #pragma unroll 8
    for (int k = 0; k < 64; ++k) s = fmaf(W2[i * 64 + k], Wlin[k * 64 + j], s);
    Wc[idx] = s;
  }
  if (tid < 64) {
    float s = blin[tid];
    #pragma unroll 8
    for (int k = 0; k < 64; ++k) s = fmaf(b2[k], Wlin[k * 64 + tid], s);
    bias_out[tid] = s;
  }
}

// ---------------- degree ------------------------------------------------------
__global__ __launch_bounds__(256) void k_deg(const int* __restrict__ dst, int n_edges,
                                             int* __restrict__ degi) {
  int t = blockIdx.x * 256 + threadIdx.x;
  if (t < n_edges) atomicAdd(&degi[dst[t]], 1);
}

__global__ __launch_bounds__(256) void k_dinv(const int* __restrict__ degi,
                                              float* __restrict__ dinv, int n) {
  int t = blockIdx.x * 256 + threadIdx.x;
  if (t < n) dinv[t] = rsqrtf((float)(degi[t] + 1));  // +1 = self loop
}

// ---------------- scan: rowptr = exclusive_scan(deg), rowptr[n] = total -------
__global__ __launch_bounds__(256) void k_scanA(const int* __restrict__ deg, int n,
                                               int* __restrict__ rowptr,
                                               int* __restrict__ partials) {
  __shared__ int sh[256];
  const int b = blockIdx.x, t = threadIdx.x;
  const int base = b * 1024 + t * 4;
  int v[4];
  int s = 0;
  #pragma unroll
  for (int k = 0; k < 4; ++k) {
    int i = base + k;
    v[k] = (i < n) ? deg[i] : 0;
    s += v[k];
  }
  sh[t] = s;
  __syncthreads();
  for (int off = 1; off < 256; off <<= 1) {
    int x = sh[t];
    int y = (t >= off) ? sh[t - off] : 0;
    __syncthreads();
    sh[t] = x + y;
    __syncthreads();
  }
  int excl = sh[t] - s;
  #pragma unroll
  for (int k = 0; k < 4; ++k) {
    int i = base + k;
    if (i < n) rowptr[i] = excl;
    excl += v[k];
  }
  if (t == 255) partials[b] = sh[255];
}

__global__ void k_scanB(int* __restrict__ partials, int nb, int* __restrict__ rowptr_n) {
  if (threadIdx.x == 0 && blockIdx.x == 0) {
    int s = 0;
    for (int i = 0; i < nb; ++i) {
      int v = partials[i];
      partials[i] = s;
      s += v;
    }
    *rowptr_n = s;
  }
}

__global__ __launch_bounds__(256) void k_scanC(int* __restrict__ rowptr,
                                               const int* __restrict__ partials, int n,
                                               int* __restrict__ cursor) {
  int i = blockIdx.x * 256 + threadIdx.x;
  if (i < n) {
    int v = rowptr[i] + partials[i >> 10];
    rowptr[i] = v;
    cursor[i] = v;
  }
}

// ---------------- bucket cursor init ------------------------------------------
__global__ __launch_bounds__(256) void k_binit(const int* __restrict__ rowptr,
                                               int* __restrict__ bcur,
                                               int n_nodes, int nbuckets) {
  int b = blockIdx.x * 256 + threadIdx.x;
  if (b < nbuckets) {
    int node = b << BKT_SHIFT;
    if (node > n_nodes) node = n_nodes;
    bcur[b] = rowptr[node];
  }
}

// ---------------- pass 1: scatter {src,dst} into dst-buckets ------------------
__global__ __launch_bounds__(256) void k_bucket(const int* __restrict__ src,
                                                const int* __restrict__ dst,
                                                int* __restrict__ bcur,
                                                int2* __restrict__ tmp, int n_edges) {
  int e = blockIdx.x * 256 + threadIdx.x;
  if (e >= n_edges) return;
  int s = src[e], d = dst[e];
  int pos = atomicAdd(&bcur[d >> BKT_SHIFT], 1);
  tmp[pos] = make_int2(s, d);
}

// ---------------- pass 2: within-bucket placement to final CSR position -------
__global__ __launch_bounds__(256) void k_place(const int2* __restrict__ tmp,
                                               const int* __restrict__ rowptr,
                                               int* __restrict__ cursor,
                                               int* __restrict__ srcs,
                                               int n_nodes) {
  int bkt = blockIdx.x;
  int n0 = bkt << BKT_SHIFT;
  int n1 = n0 + BKT_NODES;
  if (n0 > n_nodes) n0 = n_nodes;
  if (n1 > n_nodes) n1 = n_nodes;
  int beg = rowptr[n0], end = rowptr[n1];
  for (int j = beg + threadIdx.x; j < end; j += 256) {
    int2 p = tmp[j];
    int pos = atomicAdd(&cursor[p.y], 1);
    srcs[pos] = p.x;
  }
}

// ---------------- fp32 tiled GEMM: C[M,64] = A[M,K] @ B[K,64] -----------------
__global__ __launch_bounds__(256) void k_gemm(const float* __restrict__ A,
                                              const float* __restrict__ B,
                                              float* __restrict__ C,
                                              int M, int K) {
  __shared__ float As[16][68];
  __shared__ float Bs[16][64];
  const int tid = threadIdx.x;
  const int block_m = blockIdx.x * 64;
  const int tm = (tid >> 4) * 4;
  const int tn = (tid & 15) * 4;
  const int lm = tid >> 2;
  const int lk = (tid & 3) * 4;
  const int bk = tid >> 4;
  const int bn = (tid & 15) * 4;

  float acc[4][4] = {{0.f}};

  for (int k0 = 0; k0 < K; k0 += 16) {
    float4 a = make_float4(0.f, 0.f, 0.f, 0.f);
    int an = block_m + lm;
    if (an < M) a = *(const float4*)&A[(size_t)an * K + k0 + lk];
    As[lk + 0][lm] = a.x;
    As[lk + 1][lm] = a.y;
    As[lk + 2][lm] = a.z;
    As[lk + 3][lm] = a.w;
    *(float4*)&Bs[bk][bn] = *(const float4*)&B[(size_t)(k0 + bk) * 64 + bn];
    __syncthreads();
    #pragma unroll
    for (int k = 0; k < 16; ++k) {
      float4 av = *(const float4*)&As[k][tm];
      float4 bv = *(const float4*)&Bs[k][tn];
      acc[0][0] = fmaf(av.x, bv.x, acc[0][0]);
      acc[0][1] = fmaf(av.x, bv.y, acc[0][1]);
      acc[0][2] = fmaf(av.x, bv.z, acc[0][2]);
      acc[0][3] = fmaf(av.x, bv.w, acc[0][3]);
      acc[1][0] = fmaf(av.y, bv.x, acc[1][0]);
      acc[1][1] = fmaf(av.y, bv.y, acc[1][1]);
      acc[1][2] = fmaf(av.y, bv.z, acc[1][2]);
      acc[1][3] = fmaf(av.y, bv.w, acc[1][3]);
      acc[2][0] = fmaf(av.z, bv.x, acc[2][0]);
      acc[2][1] = fmaf(av.z, bv.y, acc[2][1]);
      acc[2][2] = fmaf(av.z, bv.z, acc[2][2]);
      acc[2][3] = fmaf(av.z, bv.w, acc[2][3]);
      acc[3][0] = fmaf(av.w, bv.x, acc[3][0]);
      acc[3][1] = fmaf(av.w, bv.y, acc[3][1]);
      acc[3][2] = fmaf(av.w, bv.z, acc[3][2]);
      acc[3][3] = fmaf(av.w, bv.w, acc[3][3]);
    }
    __syncthreads();
  }
  #pragma unroll
  for (int i = 0; i < 4; ++i) {
    int row = block_m + tm + i;
    if (row < M) {
      float4 r = make_float4(acc[i][0], acc[i][1], acc[i][2], acc[i][3]);
      *(float4*)&C[(size_t)row * 64 + tn] = r;
    }
  }
}

// ---- fused CSR gather + self-loop + bias (+ReLU):
//   out[n,l] = act( sum_e dinv[s_e]*dinv[n]*feat[s_e,l] + dinv[n]^2*feat[n,l] + bias[l] )
// one 64-lane wave per node, lane = feature channel
__global__ __launch_bounds__(256) void k_gather(const float* __restrict__ feat,
                                                const int* __restrict__ rowptr,
                                                const int* __restrict__ srcs,
                                                const float* __restrict__ dinv,
                                                const float* __restrict__ bias,
                                                float* __restrict__ out,
                                                int n_nodes, int relu) {
  int node = blockIdx.x * 4 + (threadIdx.x >> 6);
  int lane = threadIdx.x & 63;
  if (node >= n_nodes) return;
  int beg = rowptr[node], end = rowptr[node + 1];
  float di = dinv[node];
  float acc = 0.f;
  int j = beg;
  for (; j + 4 <= end; j += 4) {
    int s0 = srcs[j], s1 = srcs[j + 1], s2 = srcs[j + 2], s3 = srcs[j + 3];
    float w0 = dinv[s0], w1 = dinv[s1], w2 = dinv[s2], w3 = dinv[s3];
    float f0 = feat[(size_t)s0 * 64 + lane];
    float f1 = feat[(size_t)s1 * 64 + lane];
    float f2 = feat[(size_t)s2 * 64 + lane];
    float f3 = feat[(size_t)s3 * 64 + lane];
    acc = fmaf(f0, w0, acc);
    acc = fmaf(f1, w1, acc);
    acc = fmaf(f2, w2, acc);
    acc = fmaf(f3, w3, acc);
  }
  for (; j < end; ++j) {
    int s = srcs[j];
    acc = fmaf(feat[(size_t)s * 64 + lane], dinv[s], acc);
  }
  // acc currently = sum dinv[s]*feat ; scale by dinv[node], add self-loop + bias
  float self = feat[(size_t)node * 64 + lane];
  float v = fmaf(acc, di, 0.f);
  v = fmaf(self, di * di, v) + bias[lane];
  if (relu) v = fmaxf(v, 0.f);
  out[(size_t)node * 64 + lane] = v;
}

extern "C" void kernel_launch(void* const* d_in, const int* in_sizes, int n_in,
                              void* d_out, int out_size, void* d_ws, size_t ws_size,
                              hipStream_t stream) {
  const float* x    = (const float*)d_in[0];
  const int*   ei   = (const int*)d_in[1];
  const float* W1   = (const float*)d_in[2];
  const float* b1   = (const float*)d_in[3];
  const float* W2   = (const float*)d_in[4];
  const float* b2   = (const float*)d_in[5];
  const float* Wlin = (const float*)d_in[6];
  const float* blin = (const float*)d_in[7];
  float* out = (float*)d_out;

  const int n_nodes = in_sizes[0] / DIN;
  const int n_edges = in_sizes[1] / 2;
  const int* src = ei;
  const int* dst = ei + n_edges;
  const int nbuckets = (n_nodes + BKT_NODES - 1) >> BKT_SHIFT;

  char* ws = (char*)d_ws;
  const size_t featBytes = (size_t)n_nodes * DH * sizeof(float);
  size_t off = 0;
  auto alloc = [&](size_t bytes) {
    void* p = ws + off;
    off += (bytes + 255) & ~(size_t)255;
    return p;
  };
  float* bufA     = (float*)alloc(featBytes);              // h1, then h2
  float* bufB     = (float*)alloc(featBytes);              // h1r
  int2*  tmp      = (int2*)alloc((size_t)n_edges * 8);     // bucketed {src,dst}
  int*   srcs     = (int*)alloc((size_t)n_edges * 4);      // final CSR src list
  int*   degi     = (int*)alloc((size_t)n_nodes * 4);
  float* dinv     = (float*)alloc((size_t)n_nodes * 4);
  int*   rowptr   = (int*)alloc(((size_t)n_nodes + 1) * 4);
  int*   cursor   = (int*)alloc((size_t)n_nodes * 4);
  int*   bcur     = (int*)alloc((size_t)(nbuckets + 1) * 4);
  int*   partials = (int*)alloc(512 * 4);
  float* Wc       = (float*)alloc(64 * 64 * 4);
  float* bias_out = (float*)alloc(64 * 4);

  hipMemsetAsync(degi, 0, (size_t)n_nodes * 4, stream);

  k_wc<<<1, 256, 0, stream>>>(W2, b2, Wlin, blin, Wc, bias_out);
  k_deg<<<(n_edges + 255) / 256, 256, 0, stream>>>(dst, n_edges, degi);
  k_dinv<<<(n_nodes + 255) / 256, 256, 0, stream>>>(degi, dinv, n_nodes);

  const int nb = (n_nodes + 1023) / 1024;
  k_scanA<<<nb, 256, 0, stream>>>(degi, n_nodes, rowptr, partials);
  k_scanB<<<1, 64, 0, stream>>>(partials, nb, rowptr + n_nodes);
  k_scanC<<<(n_nodes + 255) / 256, 256, 0, stream>>>(rowptr, partials, n_nodes, cursor);

  k_binit<<<(nbuckets + 255) / 256, 256, 0, stream>>>(rowptr, bcur, n_nodes, nbuckets);
  k_bucket<<<(n_edges + 255) / 256, 256, 0, stream>>>(src, dst, bcur, tmp, n_edges);
  k_place<<<nbuckets, 256, 0, stream>>>(tmp, rowptr, cursor, srcs, n_nodes);

  const int gblocks = (n_nodes + 63) / 64;
  const int agblocks = (n_nodes + 3) / 4;

  // layer 1
  k_gemm<<<gblocks, 256, 0, stream>>>(x, W1, bufA, n_nodes, DIN);
  k_gather<<<agblocks, 256, 0, stream>>>(bufA, rowptr, srcs, dinv, b1, bufB, n_nodes, 1);

  // layer 2 (+ folded final linear): h2 = h1r @ (W2@Wlin)
  k_gemm<<<gblocks, 256, 0, stream>>>(bufB, Wc, bufA, n_nodes, DH);
  k_gather<<<agblocks, 256, 0, stream>>>(bufA, rowptr, srcs, dinv, bias_out, out, n_nodes, 0);
}